// Round 1
// baseline (6144.154 us; speedup 1.0000x reference)
//
#include <hip/hip_runtime.h>
#include <hip/hip_bf16.h>

// ---------------------------------------------------------------------------
// Conv-TasNet TCN, fp32 baseline.
// Pipeline per block i: 
//   A: Y = prelu(pw_w @ X) (+ GN1 stats atomics)
//   B: U = prelu(dwconv(GN1(Y))) (+ GN2 stats atomics)   [GN folded as affine]
//   C: OUT += res_w @ GN2(U);  SKIP += sk_w @ GN2(U)
// GroupNorm(1,C) normalizes over (C,T) per sample -> per-sample scalar stats,
// folded into the next kernel as per-channel affine  x*s[c] + o[c].
// ---------------------------------------------------------------------------

#define T_ 4000
#define B_ 4

// ---------------- per-sample sum/sumsq reduction over contiguous block -----
__global__ __launch_bounds__(256) void gn_stats(const float* __restrict__ X,
                                                float* __restrict__ statsOut, int n) {
  const int b = blockIdx.y;
  const float4* xp = (const float4*)(X + (size_t)b * n);
  const int n4 = n >> 2;
  float s1 = 0.f, s2 = 0.f;
  for (int idx = blockIdx.x * 256 + threadIdx.x; idx < n4; idx += gridDim.x * 256) {
    float4 v = xp[idx];
    s1 += v.x + v.y + v.z + v.w;
    s2 += v.x * v.x + v.y * v.y + v.z * v.z + v.w * v.w;
  }
  __shared__ float red[512];
  red[threadIdx.x] = s1; red[256 + threadIdx.x] = s2;
  __syncthreads();
  for (int off = 128; off > 0; off >>= 1) {
    if (threadIdx.x < off) {
      red[threadIdx.x] += red[threadIdx.x + off];
      red[256 + threadIdx.x] += red[256 + threadIdx.x + off];
    }
    __syncthreads();
  }
  if (threadIdx.x == 0) {
    atomicAdd(&statsOut[b * 2 + 0], red[0]);
    atomicAdd(&statsOut[b * 2 + 1], red[256]);
  }
}

// ---------------- pointwise GEMM:  Y[b,m,t] = act( W[m,:] . xform(X[b,:,t]) + bias[m] )
// XMODE 0: X as-is    1: GN affine from statsIn + (gv,bv)    2: prelu(alphaIn[0])
// OPRELU: prelu(alphaOutP[0]) on output.  STATS: accumulate sum/sumsq of Y into statsOut.
// Tile: BM=64 (m), BN=128 (t), BK=16; 256 threads; thread computes 4x8.
template <int XMODE, bool OPRELU, bool STATS>
__global__ __launch_bounds__(256) void pw_gemm(
    const float* __restrict__ W, const float* __restrict__ bias,
    const float* __restrict__ X, float* __restrict__ Y, int M, int K,
    const float* __restrict__ statsIn, float invN_in,
    const float* __restrict__ gv, const float* __restrict__ bv,
    const float* __restrict__ alphaIn, const float* __restrict__ alphaOutP,
    float* __restrict__ statsOut) {
  const int b  = blockIdx.z;
  const int m0 = blockIdx.y * 64;
  const int t0 = blockIdx.x * 128;
  const int tid = threadIdx.x;
  const int tx = tid & 15, ty = tid >> 4;

  __shared__ float Wl[16][68];
  __shared__ float Xl[16][132];
  __shared__ float red[512];

  float meanIn = 0.f, rsIn = 1.f;
  if (XMODE == 1) {
    float a = statsIn[b * 2], q = statsIn[b * 2 + 1];
    meanIn = a * invN_in;
    float var = q * invN_in - meanIn * meanIn;
    rsIn = rsqrtf(var + 1e-8f);
  }
  const float aIn = (XMODE == 2) ? alphaIn[0] : 0.f;

  float acc[4][8];
#pragma unroll
  for (int i = 0; i < 4; ++i)
#pragma unroll
    for (int j = 0; j < 8; ++j) acc[i][j] = 0.f;

  const float* Xb = X + (size_t)b * K * T_;

  for (int k0 = 0; k0 < K; k0 += 16) {
    { // W tile -> Wl[k][m] (transposed)
      const int mm = tid >> 2;
      const int kk4 = (tid & 3) * 4;
      float4 w4 = *(const float4*)(W + (size_t)(m0 + mm) * K + k0 + kk4);
      Wl[kk4 + 0][mm] = w4.x; Wl[kk4 + 1][mm] = w4.y;
      Wl[kk4 + 2][mm] = w4.z; Wl[kk4 + 3][mm] = w4.w;
    }
    { // X tile -> Xl[k][n], with transform
      const int kk = tid >> 4;
      const int nn = (tid & 15) * 8;
      const int t = t0 + nn;
      const float* xp = Xb + (size_t)(k0 + kk) * T_ + t;
      float v[8];
      if (t + 8 <= T_) {
        float4 x0 = *(const float4*)xp;
        float4 x1 = *(const float4*)(xp + 4);
        v[0] = x0.x; v[1] = x0.y; v[2] = x0.z; v[3] = x0.w;
        v[4] = x1.x; v[5] = x1.y; v[6] = x1.z; v[7] = x1.w;
      } else {
#pragma unroll
        for (int j = 0; j < 8; ++j) v[j] = (t + j < T_) ? xp[j] : 0.f;
      }
      if (XMODE == 1) {
        float s = rsIn * gv[k0 + kk];
        float o = bv[k0 + kk] - meanIn * s;
#pragma unroll
        for (int j = 0; j < 8; ++j) v[j] = v[j] * s + o;
      } else if (XMODE == 2) {
#pragma unroll
        for (int j = 0; j < 8; ++j) v[j] = v[j] >= 0.f ? v[j] : aIn * v[j];
      }
      *(float4*)&Xl[kk][nn]     = make_float4(v[0], v[1], v[2], v[3]);
      *(float4*)&Xl[kk][nn + 4] = make_float4(v[4], v[5], v[6], v[7]);
    }
    __syncthreads();
#pragma unroll
    for (int kk = 0; kk < 16; ++kk) {
      float4 a4 = *(const float4*)&Wl[kk][ty * 4];
      float4 x0 = *(const float4*)&Xl[kk][tx * 8];
      float4 x1 = *(const float4*)&Xl[kk][tx * 8 + 4];
      float av[4] = {a4.x, a4.y, a4.z, a4.w};
      float xv[8] = {x0.x, x0.y, x0.z, x0.w, x1.x, x1.y, x1.z, x1.w};
#pragma unroll
      for (int i = 0; i < 4; ++i)
#pragma unroll
        for (int j = 0; j < 8; ++j) acc[i][j] = fmaf(av[i], xv[j], acc[i][j]);
    }
    __syncthreads();
  }

  const float aOut = OPRELU ? alphaOutP[0] : 0.f;
  float s1 = 0.f, s2 = 0.f;
  float* Yb = Y + (size_t)b * M * T_;
  const int tbase = t0 + tx * 8;
#pragma unroll
  for (int i = 0; i < 4; ++i) {
    const int m = m0 + ty * 4 + i;
    const float bi = bias[m];
    float v[8];
#pragma unroll
    for (int j = 0; j < 8; ++j) {
      float vv = acc[i][j] + bi;
      if (OPRELU) vv = vv >= 0.f ? vv : aOut * vv;
      v[j] = vv;
    }
    float* yrow = Yb + (size_t)m * T_ + tbase;
    if (tbase + 8 <= T_) {
      *(float4*)yrow       = make_float4(v[0], v[1], v[2], v[3]);
      *(float4*)(yrow + 4) = make_float4(v[4], v[5], v[6], v[7]);
      if (STATS) {
#pragma unroll
        for (int j = 0; j < 8; ++j) { s1 += v[j]; s2 += v[j] * v[j]; }
      }
    } else {
#pragma unroll
      for (int j = 0; j < 8; ++j)
        if (tbase + j < T_) {
          yrow[j] = v[j];
          if (STATS) { s1 += v[j]; s2 += v[j] * v[j]; }
        }
    }
  }
  if (STATS) {
    red[tid] = s1; red[256 + tid] = s2;
    __syncthreads();
    for (int off = 128; off > 0; off >>= 1) {
      if (tid < off) {
        red[tid] += red[tid + off];
        red[256 + tid] += red[256 + tid + off];
      }
      __syncthreads();
    }
    if (tid == 0) {
      atomicAdd(&statsOut[b * 2 + 0], red[0]);
      atomicAdd(&statsOut[b * 2 + 1], red[256]);
    }
  }
}

// ---------------- depthwise dilated conv (K=3), GN1 affine on input, prelu out,
// GN2 stats accumulated. One block per (b,h) row; row staged in LDS with halo.
__global__ __launch_bounds__(256) void dw_kernel(
    const float* __restrict__ Y, float* __restrict__ U,
    const float* __restrict__ dww, const float* __restrict__ dwb,
    const float* __restrict__ g1, const float* __restrict__ b1,
    const float* __restrict__ p2p, const float* __restrict__ statsIn, float invN,
    float* __restrict__ statsOut, int dil) {
  const int bh = blockIdx.x;
  const int b = bh >> 9, h = bh & 511;
  const int tid = threadIdx.x;
  __shared__ float row[T_ + 256];
  __shared__ float red[512];

  const float sm = statsIn[b * 2], sq = statsIn[b * 2 + 1];
  const float mean = sm * invN;
  const float rs = rsqrtf(sq * invN - mean * mean + 1e-8f);
  const float s = rs * g1[h];
  const float o = b1[h] - mean * s;

  const float* yp = Y + ((size_t)b * 512 + h) * T_;
  for (int t = tid; t < dil; t += 256) { row[t] = 0.f; row[dil + T_ + t] = 0.f; }
  for (int t = tid; t < T_; t += 256) row[dil + t] = yp[t] * s + o;
  __syncthreads();

  const float w0 = dww[h * 3], w1 = dww[h * 3 + 1], w2 = dww[h * 3 + 2];
  const float bc = dwb[h];
  const float p2 = p2p[0];
  float* up = U + ((size_t)b * 512 + h) * T_;
  float a1 = 0.f, a2 = 0.f;
  for (int t = tid; t < T_; t += 256) {
    float v = fmaf(w0, row[t], fmaf(w1, row[t + dil], fmaf(w2, row[t + 2 * dil], bc)));
    v = v >= 0.f ? v : p2 * v;
    up[t] = v;
    a1 += v; a2 += v * v;
  }
  red[tid] = a1; red[256 + tid] = a2;
  __syncthreads();
  for (int off = 128; off > 0; off >>= 1) {
    if (tid < off) {
      red[tid] += red[tid + off];
      red[256 + tid] += red[256 + tid + off];
    }
    __syncthreads();
  }
  if (tid == 0) {
    atomicAdd(&statsOut[b * 2 + 0], red[0]);
    atomicAdd(&statsOut[b * 2 + 1], red[256]);
  }
}

// ---------------- res+skip GEMM: GN2-affine on U; OUT += res, SKIP += skip;
// optional feature_r copy of updated OUT.  Tile BM=64(c) x BN=64(t) x BK=16.
template <bool WFEAT>
__global__ __launch_bounds__(256) void res_skip_gemm(
    const float* __restrict__ Wr, const float* __restrict__ rb,
    const float* __restrict__ Ws, const float* __restrict__ sb,
    const float* __restrict__ U, float* __restrict__ OUTS, float* __restrict__ SKIP,
    float* __restrict__ FEAT, const float* __restrict__ g2, const float* __restrict__ b2,
    const float* __restrict__ statsIn, float invN) {
  const int b  = blockIdx.z;
  const int c0 = blockIdx.y * 64;
  const int t0 = blockIdx.x * 64;
  const int tid = threadIdx.x;
  const int tx = tid & 15, ty = tid >> 4;

  __shared__ float Wrl[16][68];
  __shared__ float Wsl[16][68];
  __shared__ float Xl[16][68];

  const float sm = statsIn[b * 2], sq = statsIn[b * 2 + 1];
  const float mean = sm * invN;
  const float rs = rsqrtf(sq * invN - mean * mean + 1e-8f);

  float accR[4][4], accS[4][4];
#pragma unroll
  for (int i = 0; i < 4; ++i)
#pragma unroll
    for (int j = 0; j < 4; ++j) { accR[i][j] = 0.f; accS[i][j] = 0.f; }

  const float* Ub = U + (size_t)b * 512 * T_;

  for (int k0 = 0; k0 < 512; k0 += 16) {
    {
      const int cc = tid >> 2;
      const int kk4 = (tid & 3) * 4;
      float4 wr = *(const float4*)(Wr + (size_t)(c0 + cc) * 512 + k0 + kk4);
      Wrl[kk4 + 0][cc] = wr.x; Wrl[kk4 + 1][cc] = wr.y;
      Wrl[kk4 + 2][cc] = wr.z; Wrl[kk4 + 3][cc] = wr.w;
      float4 ws = *(const float4*)(Ws + (size_t)(c0 + cc) * 512 + k0 + kk4);
      Wsl[kk4 + 0][cc] = ws.x; Wsl[kk4 + 1][cc] = ws.y;
      Wsl[kk4 + 2][cc] = ws.z; Wsl[kk4 + 3][cc] = ws.w;
    }
    {
      const int kk = tid >> 4;
      const int nn = (tid & 15) * 4;
      const int t = t0 + nn;
      const int h = k0 + kk;
      const float s = rs * g2[h];
      const float o = b2[h] - mean * s;
      const float* xp = Ub + (size_t)h * T_ + t;
      float v[4];
      if (t + 4 <= T_) {
        float4 x = *(const float4*)xp;
        v[0] = x.x; v[1] = x.y; v[2] = x.z; v[3] = x.w;
      } else {
#pragma unroll
        for (int j = 0; j < 4; ++j) v[j] = (t + j < T_) ? xp[j] : 0.f;
      }
#pragma unroll
      for (int j = 0; j < 4; ++j) v[j] = v[j] * s + o;
      *(float4*)&Xl[kk][nn] = make_float4(v[0], v[1], v[2], v[3]);
    }
    __syncthreads();
#pragma unroll
    for (int kk = 0; kk < 16; ++kk) {
      float4 ar = *(const float4*)&Wrl[kk][ty * 4];
      float4 as = *(const float4*)&Wsl[kk][ty * 4];
      float4 x  = *(const float4*)&Xl[kk][tx * 4];
      float arv[4] = {ar.x, ar.y, ar.z, ar.w};
      float asv[4] = {as.x, as.y, as.z, as.w};
      float xv[4]  = {x.x, x.y, x.z, x.w};
#pragma unroll
      for (int i = 0; i < 4; ++i)
#pragma unroll
        for (int j = 0; j < 4; ++j) {
          accR[i][j] = fmaf(arv[i], xv[j], accR[i][j]);
          accS[i][j] = fmaf(asv[i], xv[j], accS[i][j]);
        }
    }
    __syncthreads();
  }

#pragma unroll
  for (int i = 0; i < 4; ++i) {
    const int c = c0 + ty * 4 + i;
    const float rbi = rb[c], sbi = sb[c];
    const size_t base = ((size_t)b * 128 + c) * T_;
#pragma unroll
    for (int j = 0; j < 4; ++j) {
      const int t = t0 + tx * 4 + j;
      if (t < T_) {
        float ov = OUTS[base + t] + accR[i][j] + rbi;
        OUTS[base + t] = ov;
        if (WFEAT) FEAT[base + t] = ov;
        SKIP[base + t] += accS[i][j] + sbi;
      }
    }
  }
}

// ---------------------------------------------------------------------------
extern "C" void kernel_launch(void* const* d_in, const int* in_sizes, int n_in,
                              void* d_out, int out_size, void* d_ws, size_t ws_size,
                              hipStream_t stream) {
  (void)in_sizes; (void)n_in; (void)out_size; (void)ws_size;
  const float* input = (const float*)d_in[0];
  const float* ln1_g = (const float*)d_in[1];
  const float* ln1_b = (const float*)d_in[2];
  const float* bn1_w = (const float*)d_in[3];
  const float* bn1_b = (const float*)d_in[4];
  const float* pw_w  = (const float*)d_in[5];
  const float* pw_b  = (const float*)d_in[6];
  const float* dw_w  = (const float*)d_in[7];
  const float* dw_b  = (const float*)d_in[8];
  const float* res_w = (const float*)d_in[9];
  const float* res_b = (const float*)d_in[10];
  const float* sk_w  = (const float*)d_in[11];
  const float* sk_b  = (const float*)d_in[12];
  const float* p1    = (const float*)d_in[13];
  const float* p2    = (const float*)d_in[14];
  const float* n1g   = (const float*)d_in[15];
  const float* n1b   = (const float*)d_in[16];
  const float* n2g   = (const float*)d_in[17];
  const float* n2b   = (const float*)d_in[18];
  const float* h1_p  = (const float*)d_in[19];
  const float* h1_w  = (const float*)d_in[20];
  const float* h1_b  = (const float*)d_in[21];
  const float* h2_p  = (const float*)d_in[22];
  const float* h2_w  = (const float*)d_in[23];
  const float* h2_b  = (const float*)d_in[24];

  float* out1 = (float*)d_out;
  float* out2 = out1 + 4096000;   // [4,256,4000]
  float* feat = out1 + 8192000;   // [4,128,4000]

  float* ws    = (float*)d_ws;
  float* OUTS  = ws;               // [4,128,4000]
  float* SKIP  = ws + 2048000;
  float* OUT2  = ws + 4096000;
  float* SKIP2 = ws + 6144000;
  float* Ybuf  = ws + 8192000;     // [4,512,4000]
  float* Ubuf  = ws + 16384000;    // [4,512,4000]
  float* STATS = ws + 24576000;    // 65 slots x (B*2) floats

  hipMemsetAsync(STATS, 0, 65 * 8 * sizeof(float), stream);
  hipMemsetAsync(SKIP, 0, 2048000 * sizeof(float), stream);

  const float invN_in = 1.0f / (256.0f * 4000.0f);
  const float invN_h  = 1.0f / (512.0f * 4000.0f);

  gn_stats<<<dim3(64, B_), 256, 0, stream>>>(input, STATS, 256 * T_);

  // bottleneck: OUTS = bn1_w @ GN(input)
  pw_gemm<1, false, false><<<dim3(32, 2, B_), 256, 0, stream>>>(
      bn1_w, bn1_b, input, OUTS, 128, 256, STATS, invN_in, ln1_g, ln1_b,
      nullptr, nullptr, nullptr);

  auto run_block = [&](int i, float* OS, float* SK, float* FEAT) {
    const int d = 1 << (i & 7);
    float* sA = STATS + (size_t)(1 + 2 * i) * 8;
    float* sB = STATS + (size_t)(2 + 2 * i) * 8;
    pw_gemm<0, true, true><<<dim3(32, 8, B_), 256, 0, stream>>>(
        pw_w + (size_t)i * 512 * 128, pw_b + (size_t)i * 512, OS, Ybuf, 512, 128,
        nullptr, 0.f, nullptr, nullptr, nullptr, p1 + i, sA);
    dw_kernel<<<dim3(B_ * 512), 256, 0, stream>>>(
        Ybuf, Ubuf, dw_w + (size_t)i * 512 * 3, dw_b + (size_t)i * 512,
        n1g + (size_t)i * 512, n1b + (size_t)i * 512, p2 + i, sA, invN_h, sB, d);
    if (FEAT)
      res_skip_gemm<true><<<dim3(63, 2, B_), 256, 0, stream>>>(
          res_w + (size_t)i * 128 * 512, res_b + (size_t)i * 128,
          sk_w + (size_t)i * 128 * 512, sk_b + (size_t)i * 128, Ubuf, OS, SK, FEAT,
          n2g + (size_t)i * 512, n2b + (size_t)i * 512, sB, invN_h);
    else
      res_skip_gemm<false><<<dim3(63, 2, B_), 256, 0, stream>>>(
          res_w + (size_t)i * 128 * 512, res_b + (size_t)i * 128,
          sk_w + (size_t)i * 128 * 512, sk_b + (size_t)i * 128, Ubuf, OS, SK, nullptr,
          n2g + (size_t)i * 512, n2b + (size_t)i * 512, sB, invN_h);
  };

  for (int i = 0; i < 8; ++i)  run_block(i, OUTS, SKIP, (i == 7) ? feat : nullptr);
  for (int i = 8; i < 16; ++i) run_block(i, OUTS, SKIP, nullptr);

  hipMemcpyAsync(OUT2, OUTS, 2048000 * sizeof(float), hipMemcpyDeviceToDevice, stream);
  hipMemcpyAsync(SKIP2, SKIP, 2048000 * sizeof(float), hipMemcpyDeviceToDevice, stream);

  for (int i = 16; i < 24; ++i) run_block(i, OUTS, SKIP, nullptr);
  for (int i = 24; i < 32; ++i) run_block(i, OUT2, SKIP2, nullptr);

  // heads: out = h_w @ prelu(skip, h_p) + h_b
  pw_gemm<2, false, false><<<dim3(32, 4, B_), 256, 0, stream>>>(
      h1_w, h1_b, SKIP, out1, 256, 128, nullptr, 0.f, nullptr, nullptr,
      h1_p, nullptr, nullptr);
  pw_gemm<2, false, false><<<dim3(32, 4, B_), 256, 0, stream>>>(
      h2_w, h2_b, SKIP2, out2, 256, 128, nullptr, 0.f, nullptr, nullptr,
      h2_p, nullptr, nullptr);
}

// Round 2
// 2545.389 us; speedup vs baseline: 2.4138x; 2.4138x over previous
//
#include <hip/hip_runtime.h>
#include <hip/hip_bf16.h>

// ---------------------------------------------------------------------------
// Conv-TasNet TCN, bf16-MFMA version.
// Activations live in [B][T_PAD=4096][C] (time-major) layout:
//   - GEMM B-operand rows are t with contiguous channels -> no transpose
//   - MFMA D fragment (col=lane&15 -> t, rows -> 4 consecutive m) stores
//     contiguous in [t][m]
//   - depthwise conv is coalesced over channels, strided over t
// fp32: residual accumulators (OUTS/SKIP), GN stats. bf16: Y/U, weights.
// GroupNorm folded as per-channel affine into consumer staging.
// ---------------------------------------------------------------------------

#define T_  4000
#define TP_ 4096
#define B_  4

typedef __attribute__((ext_vector_type(8))) short  s8v;
typedef __attribute__((ext_vector_type(4))) float  f32x4;
typedef __attribute__((ext_vector_type(4))) unsigned short u16x4;

__device__ __forceinline__ float bf2f(unsigned short u) {
  unsigned int i = ((unsigned int)u) << 16;
  float f; __builtin_memcpy(&f, &i, 4); return f;
}
__device__ __forceinline__ unsigned short f2bf(float f) {
  unsigned int i; __builtin_memcpy(&i, &f, 4);
  unsigned int r = i + 0x7fffu + ((i >> 16) & 1u);
  return (unsigned short)(r >> 16);
}

// ---------------- per-sample sum/sumsq over contiguous [C*T] block ---------
__global__ __launch_bounds__(256) void gn_stats(const float* __restrict__ X,
                                                float* __restrict__ statsOut, int n) {
  const int b = blockIdx.y;
  const float4* xp = (const float4*)(X + (size_t)b * n);
  const int n4 = n >> 2;
  float s1 = 0.f, s2 = 0.f;
  for (int idx = blockIdx.x * 256 + threadIdx.x; idx < n4; idx += gridDim.x * 256) {
    float4 v = xp[idx];
    s1 += v.x + v.y + v.z + v.w;
    s2 += v.x * v.x + v.y * v.y + v.z * v.z + v.w * v.w;
  }
  __shared__ float red[512];
  red[threadIdx.x] = s1; red[256 + threadIdx.x] = s2;
  __syncthreads();
  for (int off = 128; off > 0; off >>= 1) {
    if (threadIdx.x < off) {
      red[threadIdx.x] += red[threadIdx.x + off];
      red[256 + threadIdx.x] += red[256 + threadIdx.x + off];
    }
    __syncthreads();
  }
  if (threadIdx.x == 0) {
    atomicAdd(&statsOut[b * 2 + 0], red[0]);
    atomicAdd(&statsOut[b * 2 + 1], red[256]);
  }
}

// ---------------- weight prep: fp32 -> bf16 --------------------------------
__global__ __launch_bounds__(256) void cvt_bf(const float* __restrict__ s,
                                              unsigned short* __restrict__ d, int n) {
  for (int i = blockIdx.x * 256 + threadIdx.x; i < n; i += gridDim.x * 256)
    d[i] = f2bf(s[i]);
}

// combined res/skip weights: d[blk][m][k], m<128 -> res, m>=128 -> skip
__global__ __launch_bounds__(256) void combine_rs(const float* __restrict__ rw,
                                                  const float* __restrict__ sw,
                                                  unsigned short* __restrict__ d) {
  const int n = 32 * 256 * 512;
  for (int i = blockIdx.x * 256 + threadIdx.x; i < n; i += gridDim.x * 256) {
    int k = i & 511;
    int m = (i >> 9) & 255;
    int blk = i >> 17;
    float v = (m < 128) ? rw[((size_t)blk * 128 + m) * 512 + k]
                        : sw[((size_t)blk * 128 + (m - 128)) * 512 + k];
    d[i] = f2bf(v);
  }
}

// ---------------- input transpose + GN affine + bf16: [b][c][t] -> [b][t][c]
__global__ __launch_bounds__(256) void tin(const float* __restrict__ X,
                                           unsigned short* __restrict__ Xt,
                                           const float* __restrict__ g,
                                           const float* __restrict__ bt,
                                           const float* __restrict__ sIn, float invN) {
  const int b = blockIdx.z, c0 = blockIdx.y * 64, t0 = blockIdx.x * 64;
  __shared__ float tile[64][65];
  const int tid = threadIdx.x;
  const float mean = sIn[b * 2] * invN;
  const float rs = rsqrtf(sIn[b * 2 + 1] * invN - mean * mean + 1e-8f);
  {
    const int cl = tid >> 2, tq = (tid & 3) * 16;
    const float* Xr = X + ((size_t)b * 256 + c0 + cl) * T_;
#pragma unroll
    for (int j = 0; j < 4; ++j) {
      int tt = t0 + tq + j * 4;
      float4 v;
      if (tt + 3 < T_) v = *(const float4*)(Xr + tt);
      else {
        v.x = (tt + 0 < T_) ? Xr[tt + 0] : 0.f;
        v.y = (tt + 1 < T_) ? Xr[tt + 1] : 0.f;
        v.z = (tt + 2 < T_) ? Xr[tt + 2] : 0.f;
        v.w = (tt + 3 < T_) ? Xr[tt + 3] : 0.f;
      }
      tile[cl][tq + j * 4 + 0] = v.x; tile[cl][tq + j * 4 + 1] = v.y;
      tile[cl][tq + j * 4 + 2] = v.z; tile[cl][tq + j * 4 + 3] = v.w;
    }
  }
  __syncthreads();
  {
    const int tl = tid >> 2, cq = (tid & 3) * 16;
    const int t = t0 + tl;
    if (t < T_) {
      unsigned short* dst = Xt + ((size_t)b * TP_ + t) * 256 + c0 + cq;
      s8v u0, u1;
#pragma unroll
      for (int j = 0; j < 16; ++j) {
        int c = c0 + cq + j;
        float sc = rs * g[c];
        float oc = bt[c] - mean * sc;
        unsigned short uu = f2bf(tile[cq + j][tl] * sc + oc);
        if (j < 8) u0[j] = (short)uu; else u1[j - 8] = (short)uu;
      }
      *(s8v*)dst = u0;
      *(s8v*)(dst + 8) = u1;
    }
  }
}

// ---------------- feature_r: OUTS [t][128] fp32 -> feat [128][t] fp32 ------
__global__ __launch_bounds__(256) void tfeat(const float* __restrict__ O,
                                             float* __restrict__ F) {
  const int b = blockIdx.z, c0 = blockIdx.y * 64, t0 = blockIdx.x * 64;
  __shared__ float tile[64][65];
  const int tid = threadIdx.x;
  {
    const int tr = tid >> 2, cq = (tid & 3) * 16;
    const int t = t0 + tr;
#pragma unroll
    for (int j = 0; j < 4; ++j) {
      float4 v = make_float4(0.f, 0.f, 0.f, 0.f);
      if (t < T_) v = *(const float4*)(O + ((size_t)b * TP_ + t) * 128 + c0 + cq + j * 4);
      tile[tr][cq + j * 4 + 0] = v.x; tile[tr][cq + j * 4 + 1] = v.y;
      tile[tr][cq + j * 4 + 2] = v.z; tile[tr][cq + j * 4 + 3] = v.w;
    }
  }
  __syncthreads();
  {
    const int cl = tid >> 2, tq = (tid & 3) * 16;
    float* Fr = F + ((size_t)b * 128 + c0 + cl) * T_;
#pragma unroll
    for (int j = 0; j < 4; ++j) {
      int tt = t0 + tq + j * 4;
      if (tt + 3 < T_) {
        float4 v = make_float4(tile[tq + j * 4 + 0][cl], tile[tq + j * 4 + 1][cl],
                               tile[tq + j * 4 + 2][cl], tile[tq + j * 4 + 3][cl]);
        *(float4*)(Fr + tt) = v;
      } else {
#pragma unroll
        for (int e = 0; e < 4; ++e)
          if (tt + e < T_) Fr[tt + e] = tile[tq + j * 4 + e][cl];
      }
    }
  }
}

// ---------------- MFMA GEMM ------------------------------------------------
// D[m][t] = A[m][k] . B(t)[k]; A bf16 [M][K]; B source per XB:
//   XB 0: fp32 [TP][K] straight        (pw input = OUTS)
//   XB 1: bf16 [TP][K] + GN affine     (res/skip input = U)
//   XB 2: fp32 [TP][K] + prelu         (heads input = SKIP)
//   XB 3: bf16 [TP][K] straight        (bn1 input = Xt)
// EPI 0: fp32 store O0[t][128] = v + bias (fresh)
// EPI 1: prelu -> bf16 store Obf[t][512]; + masked GN stats -> statsOut
// EPI 2: fp32 RMW (blockIdx.y==0 ? O0 : O1)[t][128] += v + bias
// EPI 3: masked fp32 scatter O0[b][M][4000] (original layout) = v + bias
template <int XB, int EPI>
__global__ __launch_bounds__(256) void mm(
    const unsigned short* __restrict__ A, const float* __restrict__ b0,
    const float* __restrict__ b1, const void* __restrict__ Bsrc, int K,
    float* __restrict__ O0, float* __restrict__ O1,
    unsigned short* __restrict__ Obf,
    const float* __restrict__ gv, const float* __restrict__ bv,
    const float* __restrict__ statsIn, float invN,
    const float* __restrict__ alphaB, const float* __restrict__ alphaO,
    float* __restrict__ statsOut) {
  __shared__ unsigned short As[128][72];
  __shared__ unsigned short Bs[128][72];
  const int b = blockIdx.z;
  const int m0 = blockIdx.y * 128;
  const int t0 = blockIdx.x * 128;
  const int tid = threadIdx.x;
  const int lane = tid & 63;
  const int w = tid >> 6, wm = w >> 1, wn = w & 1;
  const int lt = lane & 15, lg = lane >> 4;

  float mean = 0.f, rs = 0.f;
  if constexpr (XB == 1) {
    float a = statsIn[b * 2], q = statsIn[b * 2 + 1];
    mean = a * invN;
    rs = rsqrtf(q * invN - mean * mean + 1e-8f);
  }
  float aB = 0.f;
  if constexpr (XB == 2) aB = alphaB[0];

  f32x4 acc[4][4];
#pragma unroll
  for (int i = 0; i < 4; ++i)
#pragma unroll
    for (int j = 0; j < 4; ++j) acc[i][j] = (f32x4){0.f, 0.f, 0.f, 0.f};

  const int r0 = tid >> 3;        // 0..31
  const int kc = (tid & 7) * 8;   // 0..56

  for (int k0 = 0; k0 < K; k0 += 64) {
    // ---- A tile
#pragma unroll
    for (int it = 0; it < 4; ++it) {
      const int r = r0 + 32 * it;
      *(s8v*)&As[r][kc] = *(const s8v*)(A + (size_t)(m0 + r) * K + (k0 + kc));
    }
    // ---- B tile
    if constexpr (XB == 0 || XB == 2) {
      const float* Bp = (const float*)Bsrc + (size_t)b * TP_ * K;
#pragma unroll
      for (int it = 0; it < 4; ++it) {
        const int r = r0 + 32 * it;
        const float* p = Bp + (size_t)(t0 + r) * K + (k0 + kc);
        float4 x0 = *(const float4*)p;
        float4 x1 = *(const float4*)(p + 4);
        float v[8] = {x0.x, x0.y, x0.z, x0.w, x1.x, x1.y, x1.z, x1.w};
        s8v uv;
#pragma unroll
        for (int j2 = 0; j2 < 8; ++j2) {
          float f = v[j2];
          if constexpr (XB == 2) f = f >= 0.f ? f : aB * f;
          uv[j2] = (short)f2bf(f);
        }
        *(s8v*)&Bs[r][kc] = uv;
      }
    } else {
      const unsigned short* Bp = (const unsigned short*)Bsrc + (size_t)b * TP_ * K;
      float s8a[8], o8a[8];
      if constexpr (XB == 1) {
#pragma unroll
        for (int j2 = 0; j2 < 8; ++j2) {
          float g = gv[k0 + kc + j2], bb = bv[k0 + kc + j2];
          s8a[j2] = rs * g;
          o8a[j2] = bb - mean * s8a[j2];
        }
      }
#pragma unroll
      for (int it = 0; it < 4; ++it) {
        const int r = r0 + 32 * it;
        s8v uv = *(const s8v*)(Bp + (size_t)(t0 + r) * K + (k0 + kc));
        if constexpr (XB == 1) {
#pragma unroll
          for (int j2 = 0; j2 < 8; ++j2) {
            float f = bf2f((unsigned short)uv[j2]) * s8a[j2] + o8a[j2];
            uv[j2] = (short)f2bf(f);
          }
        }
        *(s8v*)&Bs[r][kc] = uv;
      }
    }
    __syncthreads();
    // ---- MFMA
#pragma unroll
    for (int ks = 0; ks < 2; ++ks) {
      s8v af[4], bfr[4];
#pragma unroll
      for (int i = 0; i < 4; ++i) {
        af[i]  = *(const s8v*)&As[wm * 64 + i * 16 + lt][ks * 32 + lg * 8];
        bfr[i] = *(const s8v*)&Bs[wn * 64 + i * 16 + lt][ks * 32 + lg * 8];
      }
#pragma unroll
      for (int i = 0; i < 4; ++i)
#pragma unroll
        for (int j = 0; j < 4; ++j)
          acc[i][j] = __builtin_amdgcn_mfma_f32_16x16x32_bf16(af[i], bfr[j], acc[i][j], 0, 0, 0);
    }
    __syncthreads();
  }

  // ---- epilogue
  float s1 = 0.f, s2 = 0.f;
  float aO = 0.f;
  if constexpr (EPI == 1) aO = alphaO[0];
#pragma unroll
  for (int i = 0; i < 4; ++i) {
    const int m = m0 + wm * 64 + i * 16 + lg * 4;
#pragma unroll
    for (int j = 0; j < 4; ++j) {
      const int t = t0 + wn * 64 + j * 16 + lt;
      f32x4 v = acc[i][j];
      if constexpr (EPI == 0) {
        float4 bi = *(const float4*)(b0 + m);
        float4 o4 = make_float4(v[0] + bi.x, v[1] + bi.y, v[2] + bi.z, v[3] + bi.w);
        *(float4*)(O0 + ((size_t)b * TP_ + t) * 128 + m) = o4;
      } else if constexpr (EPI == 1) {
        float4 bi = *(const float4*)(b0 + m);
        float fv[4] = {v[0] + bi.x, v[1] + bi.y, v[2] + bi.z, v[3] + bi.w};
        u16x4 pk;
#pragma unroll
        for (int r = 0; r < 4; ++r) {
          float f = fv[r];
          f = f >= 0.f ? f : aO * f;
          pk[r] = f2bf(f);
        }
        *(u16x4*)(Obf + ((size_t)b * TP_ + t) * 512 + m) = pk;
        if (t < T_) {
#pragma unroll
          for (int r = 0; r < 4; ++r) { float f = bf2f(pk[r]); s1 += f; s2 += f * f; }
        }
      } else if constexpr (EPI == 2) {
        float* P = (blockIdx.y == 0) ? O0 : O1;
        const float* bp = (blockIdx.y == 0) ? b0 : b1;
        float4 bi = *(const float4*)(bp + (m - m0));
        float4* p = (float4*)(P + ((size_t)b * TP_ + t) * 128 + (m - m0));
        float4 old = *p;
        *p = make_float4(old.x + v[0] + bi.x, old.y + v[1] + bi.y,
                         old.z + v[2] + bi.z, old.w + v[3] + bi.w);
      } else {
        if (t < T_) {
          const int Mtot = gridDim.y * 128;
#pragma unroll
          for (int r = 0; r < 4; ++r)
            O0[((size_t)b * Mtot + (m + r)) * T_ + t] = v[r] + b0[m + r];
        }
      }
    }
  }
  if constexpr (EPI == 1) {
    __shared__ float red[512];
    red[tid] = s1; red[256 + tid] = s2;
    __syncthreads();
    for (int off = 128; off > 0; off >>= 1) {
      if (tid < off) {
        red[tid] += red[tid + off];
        red[256 + tid] += red[256 + tid + off];
      }
      __syncthreads();
    }
    if (tid == 0) {
      atomicAdd(&statsOut[b * 2 + 0], red[0]);
      atomicAdd(&statsOut[b * 2 + 1], red[256]);
    }
  }
}

// ---------------- depthwise dilated conv, [t][h] layout ---------------------
// U[t][h] = bf16( prelu( sum_j w_j[h] * GN1affine(Y[t+(j-1)*d][h]) + b[h] ) )
// OOB taps are zero (post-GN zero padding, as in reference). GN2 stats out.
__global__ __launch_bounds__(256) void dw2(
    const unsigned short* __restrict__ Y, unsigned short* __restrict__ U,
    const float* __restrict__ dww, const float* __restrict__ dwb,
    const float* __restrict__ g1, const float* __restrict__ b1,
    const float* __restrict__ p2p, const float* __restrict__ sIn, float invN,
    float* __restrict__ sOut, int dil) {
  const int b = blockIdx.y;
  const int tid = threadIdx.x;
  const int hc = (tid & 63) * 8;
  const int tbase = blockIdx.x * 16 + (tid >> 6) * 4;

  const float mean = sIn[b * 2] * invN;
  const float rs = rsqrtf(sIn[b * 2 + 1] * invN - mean * mean + 1e-8f);
  float sA[8], oA[8], w0[8], w1[8], w2[8], bb[8];
#pragma unroll
  for (int j = 0; j < 8; ++j) {
    sA[j] = rs * g1[hc + j];
    oA[j] = b1[hc + j] - mean * sA[j];
    w0[j] = dww[(hc + j) * 3 + 0];
    w1[j] = dww[(hc + j) * 3 + 1];
    w2[j] = dww[(hc + j) * 3 + 2];
    bb[j] = dwb[hc + j];
  }
  const float alpha = p2p[0];
  const unsigned short* Yb = Y + (size_t)b * TP_ * 512;
  unsigned short* Ub = U + (size_t)b * TP_ * 512;
  float s1 = 0.f, s2 = 0.f;
#pragma unroll
  for (int i = 0; i < 4; ++i) {
    const int t = tbase + i;
    const int tm = t - dil, tp = t + dil;
    const bool vm = (tm >= 0), vp = (tp < T_);
    s8v xm = {0, 0, 0, 0, 0, 0, 0, 0};
    s8v xp = {0, 0, 0, 0, 0, 0, 0, 0};
    s8v x0 = *(const s8v*)(Yb + (size_t)t * 512 + hc);
    if (vm) xm = *(const s8v*)(Yb + (size_t)tm * 512 + hc);
    if (vp) xp = *(const s8v*)(Yb + (size_t)tp * 512 + hc);
    s8v out;
#pragma unroll
    for (int j = 0; j < 8; ++j) {
      float fm = vm ? (bf2f((unsigned short)xm[j]) * sA[j] + oA[j]) : 0.f;
      float f0 = bf2f((unsigned short)x0[j]) * sA[j] + oA[j];
      float fp = vp ? (bf2f((unsigned short)xp[j]) * sA[j] + oA[j]) : 0.f;
      float v = fmaf(w0[j], fm, fmaf(w1[j], f0, fmaf(w2[j], fp, bb[j])));
      v = v >= 0.f ? v : alpha * v;
      unsigned short u = f2bf(v);
      out[j] = (short)u;
      float f = bf2f(u);
      s1 += f; s2 += f * f;
    }
    *(s8v*)(Ub + (size_t)t * 512 + hc) = out;
  }
  __shared__ float red[512];
  red[tid] = s1; red[256 + tid] = s2;
  __syncthreads();
  for (int off = 128; off > 0; off >>= 1) {
    if (tid < off) {
      red[tid] += red[tid + off];
      red[256 + tid] += red[256 + tid + off];
    }
    __syncthreads();
  }
  if (tid == 0) {
    atomicAdd(&sOut[b * 2 + 0], red[0]);
    atomicAdd(&sOut[b * 2 + 1], red[256]);
  }
}

// ---------------------------------------------------------------------------
extern "C" void kernel_launch(void* const* d_in, const int* in_sizes, int n_in,
                              void* d_out, int out_size, void* d_ws, size_t ws_size,
                              hipStream_t stream) {
  (void)in_sizes; (void)n_in; (void)out_size; (void)ws_size;
  const float* input = (const float*)d_in[0];
  const float* ln1_g = (const float*)d_in[1];
  const float* ln1_b = (const float*)d_in[2];
  const float* bn1_w = (const float*)d_in[3];
  const float* bn1_b = (const float*)d_in[4];
  const float* pw_w  = (const float*)d_in[5];
  const float* pw_b  = (const float*)d_in[6];
  const float* dw_w  = (const float*)d_in[7];
  const float* dw_b  = (const float*)d_in[8];
  const float* res_w = (const float*)d_in[9];
  const float* res_b = (const float*)d_in[10];
  const float* sk_w  = (const float*)d_in[11];
  const float* sk_b  = (const float*)d_in[12];
  const float* p1    = (const float*)d_in[13];
  const float* p2    = (const float*)d_in[14];
  const float* n1g   = (const float*)d_in[15];
  const float* n1b   = (const float*)d_in[16];
  const float* n2g   = (const float*)d_in[17];
  const float* n2b   = (const float*)d_in[18];
  const float* h1_p  = (const float*)d_in[19];
  const float* h1_w  = (const float*)d_in[20];
  const float* h1_b  = (const float*)d_in[21];
  const float* h2_p  = (const float*)d_in[22];
  const float* h2_w  = (const float*)d_in[23];
  const float* h2_b  = (const float*)d_in[24];

  float* out1 = (float*)d_out;
  float* out2 = out1 + 4096000;   // [4,256,4000]
  float* feat = out1 + 8192000;   // [4,128,4000]

  char* base = (char*)d_ws;
  float* OUTS  = (float*)base;                 base += (size_t)B_ * TP_ * 128 * 4;
  float* SKIP  = (float*)base;                 base += (size_t)B_ * TP_ * 128 * 4;
  float* OUT2  = (float*)base;                 base += (size_t)B_ * TP_ * 128 * 4;
  float* SKIP2 = (float*)base;                 base += (size_t)B_ * TP_ * 128 * 4;
  unsigned short* Ybuf = (unsigned short*)base; base += (size_t)B_ * TP_ * 512 * 2;
  unsigned short* Ubuf = (unsigned short*)base; base += (size_t)B_ * TP_ * 512 * 2;
  unsigned short* Xt   = (unsigned short*)base; base += (size_t)B_ * TP_ * 256 * 2;
  unsigned short* Wpw  = (unsigned short*)base; base += (size_t)32 * 512 * 128 * 2;
  unsigned short* Wrs  = (unsigned short*)base; base += (size_t)32 * 256 * 512 * 2;
  unsigned short* Wbn  = (unsigned short*)base; base += (size_t)128 * 256 * 2;
  unsigned short* Wh1  = (unsigned short*)base; base += (size_t)256 * 128 * 2;
  unsigned short* Wh2  = (unsigned short*)base; base += (size_t)256 * 128 * 2;
  float* STATS = (float*)base;

  hipMemsetAsync(STATS, 0, 65 * 8 * sizeof(float), stream);
  hipMemsetAsync(SKIP, 0, (size_t)B_ * TP_ * 128 * sizeof(float), stream);

  const float invN_in = 1.0f / (256.0f * 4000.0f);
  const float invN_h  = 1.0f / (512.0f * 4000.0f);

  // weight prep
  cvt_bf<<<2048, 256, 0, stream>>>(pw_w, Wpw, 32 * 512 * 128);
  cvt_bf<<<128, 256, 0, stream>>>(bn1_w, Wbn, 128 * 256);
  cvt_bf<<<128, 256, 0, stream>>>(h1_w, Wh1, 256 * 128);
  cvt_bf<<<128, 256, 0, stream>>>(h2_w, Wh2, 256 * 128);
  combine_rs<<<4096, 256, 0, stream>>>(res_w, sk_w, Wrs);

  // input GN stats -> transpose/affine/bf16 -> bottleneck GEMM
  gn_stats<<<dim3(64, B_), 256, 0, stream>>>(input, STATS, 256 * T_);
  tin<<<dim3(63, 4, B_), 256, 0, stream>>>(input, Xt, ln1_g, ln1_b, STATS, invN_in);
  mm<3, 0><<<dim3(32, 1, B_), 256, 0, stream>>>(
      Wbn, bn1_b, nullptr, Xt, 256, OUTS, nullptr, nullptr,
      nullptr, nullptr, nullptr, 0.f, nullptr, nullptr, nullptr);

  auto run_block = [&](int i, float* OS, float* SK) {
    float* sA = STATS + (size_t)(1 + 2 * i) * 8;
    float* sB = STATS + (size_t)(2 + 2 * i) * 8;
    mm<0, 1><<<dim3(32, 4, B_), 256, 0, stream>>>(
        Wpw + (size_t)i * 512 * 128, pw_b + (size_t)i * 512, nullptr, OS, 128,
        nullptr, nullptr, Ybuf, nullptr, nullptr, nullptr, 0.f,
        nullptr, p1 + i, sA);
    dw2<<<dim3(250, B_), 256, 0, stream>>>(
        Ybuf, Ubuf, dw_w + (size_t)i * 512 * 3, dw_b + (size_t)i * 512,
        n1g + (size_t)i * 512, n1b + (size_t)i * 512, p2 + i, sA, invN_h, sB,
        1 << (i & 7));
    mm<1, 2><<<dim3(32, 2, B_), 256, 0, stream>>>(
        Wrs + (size_t)i * 256 * 512, res_b + (size_t)i * 128, sk_b + (size_t)i * 128,
        Ubuf, 512, OS, SK, nullptr, n2g + (size_t)i * 512, n2b + (size_t)i * 512,
        sB, invN_h, nullptr, nullptr, nullptr);
  };

  for (int i = 0; i < 8; ++i) {
    run_block(i, OUTS, SKIP);
    if (i == 7) tfeat<<<dim3(63, 2, B_), 256, 0, stream>>>(OUTS, feat);
  }
  for (int i = 8; i < 16; ++i) run_block(i, OUTS, SKIP);

  hipMemcpyAsync(OUT2, OUTS, (size_t)B_ * TP_ * 128 * 4, hipMemcpyDeviceToDevice, stream);
  hipMemcpyAsync(SKIP2, SKIP, (size_t)B_ * TP_ * 128 * 4, hipMemcpyDeviceToDevice, stream);

  for (int i = 16; i < 24; ++i) run_block(i, OUTS, SKIP);
  for (int i = 24; i < 32; ++i) run_block(i, OUT2, SKIP2);

  // heads
  mm<2, 3><<<dim3(32, 2, B_), 256, 0, stream>>>(
      Wh1, h1_b, nullptr, SKIP, 128, out1, nullptr, nullptr,
      nullptr, nullptr, nullptr, 0.f, h1_p, nullptr, nullptr);
  mm<2, 3><<<dim3(32, 2, B_), 256, 0, stream>>>(
      Wh2, h2_b, nullptr, SKIP2, 128, out2, nullptr, nullptr,
      nullptr, nullptr, nullptr, 0.f, h2_p, nullptr, nullptr);
}